// Round 1
// baseline (179.879 us; speedup 1.0000x reference)
//
#include <hip/hip_runtime.h>

#define N_ROWS 32768
#define DIM    2048
#define KSEL   1638
#define MPAD   1664   // KSEL padded to multiple of 128
#define ZHALF  16384  // rows zeroed per GEMM kernel
#define ZROWS  40     // out-rows zeroed per GEMM block (416*40 >= 16384)

typedef __attribute__((ext_vector_type(4))) float          f32x4;
typedef __attribute__((ext_vector_type(4))) unsigned short us4;
typedef __attribute__((ext_vector_type(8))) unsigned short us8;
typedef __bf16 bf16x8 __attribute__((ext_vector_type(8)));

__device__ __forceinline__ unsigned short f2bf(float f) {
    unsigned u = __float_as_uint(f);
    u += 0x7FFFu + ((u >> 16) & 1u);   // RNE
    return (unsigned short)(u >> 16);
}

__device__ __forceinline__ void gload_lds16(const void* g, void* l) {
    __builtin_amdgcn_global_load_lds(
        (const __attribute__((address_space(1))) unsigned int*)(uintptr_t)g,
        (__attribute__((address_space(3))) unsigned int*)(uintptr_t)l, 16, 0, 0);
}

// ---------------- prep: gate dot-products + W transpose/convert + mask zero
// The harness re-poisons the out allocation every iteration (fill dispatch
// WRITE_SIZE == 4x out_size), so the old mask-based "dirty row" trick always
// degenerated to a full 268 MB zero inside the BW-bound gate kernel.
// New scheme: gate is a pure read stream; the 268 MB out-zeroing moves into
// the compute-bound GEMMs (see gemm_k) where it hides under MFMA.
// Block partition: [0,8192) gate (4 rows each), [8192,10240) convt,
// [10240,10272) mask zeroing (unconditional -- poison-safe).
__global__ __launch_bounds__(256) void prep_k(const float* __restrict__ x,
                                              const float* __restrict__ Wg,
                                              const float* __restrict__ bg,
                                              float* __restrict__ scores,
                                              const float* __restrict__ W1,
                                              const float* __restrict__ W2,
                                              unsigned short* __restrict__ W1t,
                                              unsigned short* __restrict__ W2t,
                                              float* __restrict__ mask) {
    __shared__ unsigned short tile[64][72];   // +8 pad: conflict-free transpose
    const int b = blockIdx.x;
    const int t = threadIdx.x;
    if (b < 8192) {
        // ---- gate: one wave per row, 4 rows per block, pure streaming ----
        const int lane = t & 63, wid = t >> 6;
        const int row = b * 4 + wid;
        const float* xr = x + (size_t)row * DIM;
        float acc = 0.f;
#pragma unroll
        for (int i = 0; i < 8; ++i) {
            const int c = i * 256 + lane * 4;
            f32x4 a = __builtin_nontemporal_load((const f32x4*)&xr[c]);
            f32x4 w = *(const f32x4*)&Wg[c];
#pragma unroll
            for (int j = 0; j < 4; ++j) acc = fmaf(a[j], w[j], acc);
        }
#pragma unroll
        for (int off = 32; off >= 1; off >>= 1) acc += __shfl_down(acc, off);
        if (lane == 0) scores[row] = acc + bg[0];
    } else if (b < 8192 + 2048) {
        // ---- convert + transpose W (f32 [k][n] -> bf16 [n][k]) ----
        const int cb = b - 8192;
        const int z = cb >> 10;            // 0: W1, 1: W2
        const int rem = cb & 1023;
        const int k0 = (rem & 31) * 64;
        const int n0 = (rem >> 5) * 64;
        const float* W = z ? W2 : W1;
        unsigned short* Wt = z ? W2t : W1t;
        {
            const int r = t >> 4, c = (t & 15) * 4;
#pragma unroll
            for (int p = 0; p < 4; ++p) {
                const int rr = p * 16 + r;
                f32x4 v = *(const f32x4*)&W[(size_t)(k0 + rr) * DIM + n0 + c];
#pragma unroll
                for (int j = 0; j < 4; ++j) tile[rr][c + j] = f2bf(v[j]);
            }
        }
        __syncthreads();
        {
            const int n = t >> 4, kk = (t & 15) * 4;
#pragma unroll
            for (int p = 0; p < 4; ++p) {
                const int nn = p * 16 + n;
                us4 o;
#pragma unroll
                for (int j = 0; j < 4; ++j) o[j] = tile[kk + j][nn];
                *(us4*)&Wt[(size_t)(n0 + nn) * DIM + k0 + kk] = o;
            }
        }
    } else {
        // ---- zero mask: 32 blocks x 256 thr x 16 B = 128 KiB ----
        const int mb = b - (8192 + 2048);
        const f32x4 zf = {};
        __builtin_nontemporal_store(zf, (f32x4*)&mask[(size_t)mb * 1024 + t * 4]);
    }
}

// ---------------- top-K select (single block, keys in registers) ------
__global__ __launch_bounds__(1024) void select_k(const float* __restrict__ scores,
                                                 int* __restrict__ sel) {
    const int t = threadIdx.x;
    const int lane = t & 63, wid = t >> 6;
    unsigned key[32];
    unsigned kmin = 0xFFFFFFFFu, kmax = 0u;
#pragma unroll
    for (int i = 0; i < 8; ++i) {
        f32x4 v = *(const f32x4*)&scores[t * 32 + i * 4];
#pragma unroll
        for (int j = 0; j < 4; ++j) {
            unsigned u = __float_as_uint(v[j]);
            u = (u & 0x80000000u) ? ~u : (u | 0x80000000u);
            key[i * 4 + j] = u;
            kmin = min(kmin, u);
            kmax = max(kmax, u);
        }
    }
#pragma unroll
    for (int off = 32; off >= 1; off >>= 1) {
        kmin = min(kmin, (unsigned)__shfl_down((int)kmin, off));
        kmax = max(kmax, (unsigned)__shfl_down((int)kmax, off));
    }
    __shared__ unsigned wmin[16], wmax[16];
    __shared__ unsigned cnt[40];
    __shared__ unsigned gmin, gmax;
    if (t < 40) cnt[t] = 0u;
    if (lane == 0) { wmin[wid] = kmin; wmax[wid] = kmax; }
    __syncthreads();
    if (t == 0) {
        unsigned mn = wmin[0], mx = wmax[0];
        for (int w = 1; w < 16; ++w) { mn = min(mn, wmin[w]); mx = max(mx, wmax[w]); }
        gmin = mn; gmax = mx;
    }
    __syncthreads();
    unsigned lo = gmin, hi = gmax;
    int it = 0;
    while (lo < hi) {
        const unsigned mid = (unsigned)(((unsigned long long)lo + hi + 1ull) >> 1);
        int c = 0;
#pragma unroll
        for (int i = 0; i < 32; ++i) c += (key[i] >= mid) ? 1 : 0;
#pragma unroll
        for (int off = 32; off >= 1; off >>= 1) c += __shfl_down(c, off);
        if (lane == 0) atomicAdd(&cnt[it], (unsigned)c);
        __syncthreads();
        const unsigned total = cnt[it];
        if (total >= (unsigned)KSEL) lo = mid; else hi = mid - 1;
        ++it;   // fresh counter slot each iter -> one barrier per iter
    }
    const unsigned kv = lo;   // K-th largest key
    __shared__ unsigned ctr, ectr;
    __shared__ int eq[256];
    if (t == 0) { ctr = 0; ectr = 0; }
    __syncthreads();
#pragma unroll
    for (int i = 0; i < 32; ++i) {
        const unsigned k = key[i];
        if (k > kv) {
            unsigned p = atomicAdd(&ctr, 1u);
            sel[p] = t * 32 + i;
        } else if (k == kv) {
            unsigned p = atomicAdd(&ectr, 1u);
            if (p < 256u) eq[p] = t * 32 + i;
        }
    }
    __syncthreads();
    if (t == 0) {   // ties at kv: take smallest indices (lax.top_k stability)
        const int C = (int)ctr;
        const int R = KSEL - C;
        const int E = (int)(ectr < 256u ? ectr : 256u);
        for (int r = 0; r < R; ++r) {
            int mi = r;
            for (int j = r + 1; j < E; ++j)
                if (eq[j] < eq[mi]) mi = j;
            int tmp = eq[r]; eq[r] = eq[mi]; eq[mi] = tmp;
            sel[C + r] = eq[r];
        }
    }
}

// ---------------- gather active rows -> bf16 A, write mask ------------
__global__ __launch_bounds__(256) void gather_k(const float* __restrict__ x,
                                                const int* __restrict__ sel,
                                                unsigned short* __restrict__ Abf,
                                                float* __restrict__ mask) {
    const int b = blockIdx.x, t = threadIdx.x;
    unsigned short* dst = Abf + (size_t)b * DIM + t * 8;
    if (b < KSEL) {
        const int src = sel[b];
        if (t == 0) mask[src] = 1.0f;
        const float* xr = x + (size_t)src * DIM + t * 8;
        f32x4 v0 = *(const f32x4*)xr;
        f32x4 v1 = *(const f32x4*)(xr + 4);
        us8 o;
#pragma unroll
        for (int j = 0; j < 4; ++j) { o[j] = f2bf(v0[j]); o[j + 4] = f2bf(v1[j]); }
        *(us8*)dst = o;
    } else {
        us8 z = {};
        *(us8*)dst = z;   // zero pad rows so GEMM tiles are full
    }
}

// ---------------- GEMM: C[MPAD x DIM] = A[MPAD x DIM] * Bt^T ----------
// 128x64 tile, BK=32, 4 waves (2Mx2N, 64x32 each), 16x16x32 bf16 MFMA.
// 416 blocks -> ~2 blocks/CU; the other block's MFMA hides this block's
// vmcnt(0) barrier drain.
// Zero-offload: each block also zeros ZROWS rows of the poisoned out
// buffer (mask-checked: selected rows are untouched, the gemm<1> scatter
// is their sole writer -> race-free). 2 fire-and-forget f32x4 store
// rounds per K-iter hide the 2x134 MB of writes under the MFMA stream.
// EPI=0: H = relu(A*W1 + b1) -> bf16, zeros out rows [0, ZHALF).
// EPI=1: scatter f32 rows of A*W2+b2, zeros out rows [ZHALF, 2*ZHALF).
template <int EPI>
__global__ __launch_bounds__(256, 2) void gemm_k(const unsigned short* __restrict__ A,
                                                 const unsigned short* __restrict__ Bt,
                                                 const float* __restrict__ bias,
                                                 unsigned short* __restrict__ Hout,
                                                 float* __restrict__ Cout,
                                                 const int* __restrict__ sel,
                                                 const float* __restrict__ mask,
                                                 float* __restrict__ zout) {
    __shared__ unsigned short lA[2][128 * 32];
    __shared__ unsigned short lB[2][64 * 32];
    __shared__ float smask[ZROWS];
    const int t = threadIdx.x;
    const int lane = t & 63;
    const int wid = t >> 6;
    const int m0 = blockIdx.x * 128;
    const int n0 = blockIdx.y * 64;
    const int wm = (wid >> 1) * 64;
    const int wn = (wid & 1) * 32;

    // zero-offload setup: block owns ZROWS rows of its out half
    const int bid = blockIdx.x + (int)gridDim.x * blockIdx.y;   // 0..415
    const int zrow0 = (EPI ? ZHALF : 0) + bid * ZROWS;
    if (t < ZROWS) {
        const int rrel = bid * ZROWS + t;
        smask[t] = (rrel < ZHALF) ? mask[zrow0 + t] : 1.0f;  // 1.0 -> skip
    }
    float* zptr = zout + (size_t)zrow0 * DIM + t * 4;

    f32x4 acc[4][2] = {};

    const int e0 = t, e1 = t + 256;
    const unsigned short* gA0 = A + (size_t)(m0 + (e0 >> 2)) * DIM + (e0 & 3) * 8;
    const unsigned short* gA1 = A + (size_t)(m0 + (e1 >> 2)) * DIM + (e1 & 3) * 8;
    const unsigned short* gB0 = Bt + (size_t)(n0 + (t >> 2)) * DIM + (t & 3) * 8;
    const int lo0 = e0 * 8, lo1 = e1 * 8, lob = t * 8;

    const int aoff = (wm + (lane & 15)) * 32 + (lane >> 4) * 8;
    const int boff = (wn + (lane & 15)) * 32 + (lane >> 4) * 8;

    // prologue: stage k=0 into buf 0 (smask LDS write covered by barrier)
    gload_lds16(gA0, &lA[0][lo0]);
    gload_lds16(gA1, &lA[0][lo1]);
    gload_lds16(gB0, &lB[0][lob]);
    __syncthreads();

    int cur = 0, zr = 0;
    const f32x4 zf = {};
    for (int k0 = 0; k0 < DIM; k0 += 32) {
        if (k0 + 32 < DIM) {   // issue next tile's loads before compute
            const int nxt = cur ^ 1, kn = k0 + 32;
            gload_lds16(gA0 + kn, &lA[nxt][lo0]);
            gload_lds16(gA1 + kn, &lA[nxt][lo1]);
            gload_lds16(gB0 + kn, &lB[nxt][lob]);
        }
        // zero-offload: 2 store rounds per iter, done after 40 of 64 iters
#pragma unroll
        for (int u = 0; u < 2; ++u) {
            if (zr < 2 * ZROWS) {
                const int rr = zr >> 1;                    // wave-uniform
                if (__float_as_uint(smask[rr]) == 0u)      // LDS broadcast
                    __builtin_nontemporal_store(
                        zf, (f32x4*)(zptr + (size_t)rr * DIM + (zr & 1) * 1024));
                ++zr;
            }
        }
        bf16x8 af[4], bfr[2];
#pragma unroll
        for (int mf = 0; mf < 4; ++mf)
            af[mf] = *(const bf16x8*)&lA[cur][aoff + mf * 16 * 32];
#pragma unroll
        for (int nf = 0; nf < 2; ++nf)
            bfr[nf] = *(const bf16x8*)&lB[cur][boff + nf * 16 * 32];
#pragma unroll
        for (int mf = 0; mf < 4; ++mf)
#pragma unroll
            for (int nf = 0; nf < 2; ++nf)
                acc[mf][nf] = __builtin_amdgcn_mfma_f32_16x16x32_bf16(
                    af[mf], bfr[nf], acc[mf][nf], 0, 0, 0);
        __syncthreads();   // drains vmcnt(0): next buffer ready, prev reads done
        cur ^= 1;
    }

#pragma unroll
    for (int mf = 0; mf < 4; ++mf) {
        const int rbase = m0 + wm + mf * 16 + (lane >> 4) * 4;
#pragma unroll
        for (int nf = 0; nf < 2; ++nf) {
            const int col = n0 + wn + nf * 16 + (lane & 15);
            const float bv = bias[col];
            if (EPI == 0) {
#pragma unroll
                for (int j = 0; j < 4; ++j) {
                    float v = acc[mf][nf][j] + bv;
                    v = fmaxf(v, 0.f);
                    Hout[(size_t)(rbase + j) * DIM + col] = f2bf(v);
                }
            } else {
#pragma unroll
                for (int j = 0; j < 4; ++j) {
                    const int r = rbase + j;
                    if (r < KSEL) {
                        __builtin_nontemporal_store(
                            acc[mf][nf][j] + bv,
                            &Cout[(size_t)sel[r] * DIM + col]);
                    }
                }
            }
        }
    }
}

extern "C" void kernel_launch(void* const* d_in, const int* in_sizes, int n_in,
                              void* d_out, int out_size, void* d_ws, size_t ws_size,
                              hipStream_t stream) {
    const float* x  = (const float*)d_in[0];
    const float* W1 = (const float*)d_in[1];
    const float* b1 = (const float*)d_in[2];
    const float* W2 = (const float*)d_in[3];
    const float* b2 = (const float*)d_in[4];
    const float* Wg = (const float*)d_in[5];
    const float* bg = (const float*)d_in[6];
    float* out  = (float*)d_out;
    float* mask = out + (size_t)N_ROWS * DIM;

    char* w = (char*)d_ws;
    float* scores = (float*)w;           w += (size_t)N_ROWS * 4;
    int* sel = (int*)w;                  w += 2048 * 4;
    unsigned short* Abf = (unsigned short*)w;  w += (size_t)MPAD * DIM * 2;
    unsigned short* Hbf = (unsigned short*)w;  w += (size_t)MPAD * DIM * 2;
    unsigned short* W1t = (unsigned short*)w;  w += (size_t)DIM * DIM * 2;
    unsigned short* W2t = (unsigned short*)w;  w += (size_t)DIM * DIM * 2;

    // gate + convt + mask-zero fused (gate no longer touches out/mask)
    hipLaunchKernelGGL(prep_k, dim3(8192 + 2048 + 32), dim3(256), 0, stream,
                       x, Wg, bg, scores, W1, W2, W1t, W2t, mask);
    hipLaunchKernelGGL(select_k, dim3(1), dim3(1024), 0, stream, scores, sel);
    hipLaunchKernelGGL(gather_k, dim3(MPAD), dim3(256), 0, stream, x, sel, Abf, mask);
    // gemm<0> zeros out rows [0, ZHALF); gemm<1> zeros [ZHALF, N) + scatters
    hipLaunchKernelGGL((gemm_k<0>), dim3(MPAD / 128, DIM / 64), dim3(256), 0, stream,
                       Abf, W1t, b1, Hbf, (float*)nullptr, (const int*)nullptr,
                       mask, out);
    hipLaunchKernelGGL((gemm_k<1>), dim3(MPAD / 128, DIM / 64), dim3(256), 0, stream,
                       Hbf, W2t, b2, (unsigned short*)nullptr, out, sel,
                       mask, out);
}